// Round 5
// baseline (511.424 us; speedup 1.0000x reference)
//
#include <hip/hip_runtime.h>
#include <hip/hip_bf16.h>

// Problem constants: B=4, H=W=256, C=64, OC=64, K=3, PAD=1
#define FEAT_N (4*64*256*256)
#define OFFS_N (4*18*256*256)
#define WTF_N  (576*64)            // deform weights, bf16, MFMA-B-fragment order
#define WT2_N  (576*20)            // offset-conv weights transposed [ic*9+t][oc pad 20]

typedef __attribute__((ext_vector_type(8))) short short8;
typedef __attribute__((ext_vector_type(4))) float float4v;
typedef __attribute__((ext_vector_type(2))) float f2;

__device__ __forceinline__ unsigned short f2bf(float f) {
    union { float f; unsigned u; } c; c.f = f;
    unsigned r = c.u + 0x7FFF + ((c.u >> 16) & 1);   // RNE
    return (unsigned short)(r >> 16);
}

__device__ __forceinline__ unsigned pack_bf16x2(float lo, float hi) {
    float2 v; v.x = lo; v.y = hi;
    __hip_bfloat162 h = __float22bfloat162_rn(v);     // v_cvt_pk_bf16_f32 on gfx950
    union { __hip_bfloat162 h; unsigned u; } c; c.h = h;
    return c.u;
}

// ---------------------------------------------------------------------------
// Weight prep (unchanged)
// ---------------------------------------------------------------------------
__global__ __launch_bounds__(256) void prep_weights(const float* __restrict__ dw,
                                                    const float* __restrict__ ow,
                                                    unsigned short* __restrict__ wtf,
                                                    float* __restrict__ wt2) {
    int idx = blockIdx.x * 256 + threadIdx.x;
    if (idx < WTF_N) {
        int j    = idx & 7;
        int lane = (idx >> 3) & 63;
        int nt   = (idx >> 9) & 3;
        int ks   = idx >> 11;
        int k    = ks * 32 + ((lane >> 4) << 3) + j;
        int tap  = k >> 6;
        int ic   = k & 63;
        int n    = nt * 16 + (lane & 15);
        wtf[idx] = f2bf(dw[n * 576 + ic * 9 + tap]);
    }
    int i2 = idx - WTF_N;
    if (i2 >= 0 && i2 < WT2_N) {
        int t  = i2 / 20;
        int oc = i2 - t * 20;
        wt2[i2] = (oc < 18) ? ow[oc * 576 + t] : 0.f;
    }
}

// ---------------------------------------------------------------------------
// conv1 (unchanged)
// ---------------------------------------------------------------------------
__global__ __launch_bounds__(256) void conv1_kernel(const float* __restrict__ x,
                                                    const float* __restrict__ cw,
                                                    const float* __restrict__ cb,
                                                    float* __restrict__ feat) {
    __shared__ __align__(16) float wl[64 * 28];
    __shared__ float bl[64];
    const int tid = threadIdx.x;
    for (int i = tid; i < 64 * 28; i += 256) {
        int oc = i / 28;
        int t  = i - oc * 28;
        wl[i] = (t < 27) ? cw[oc * 27 + t] : 0.f;
    }
    if (tid < 64) bl[tid] = cb[tid];
    __syncthreads();

    const int bx = blockIdx.x;
    const int b  = bx >> 7;
    const int h0 = (bx & 127) << 1;
    const int w  = tid;

    float xr[3][4][3];
#pragma unroll
    for (int ic = 0; ic < 3; ic++) {
#pragma unroll
        for (int r = 0; r < 4; r++) {
            int row = h0 - 1 + r;
            bool rok = (unsigned)row < 256u;
#pragma unroll
            for (int j = 0; j < 3; j++) {
                int col = w - 1 + j;
                bool ok = rok && ((unsigned)col < 256u);
                xr[ic][r][j] = ok ? x[((b * 3 + ic) << 16) + (row << 8) + col] : 0.f;
            }
        }
    }

    for (int oc = 0; oc < 64; oc++) {
        float aA = bl[oc];
        float aB = aA;
        const float* wp = &wl[oc * 28];
#pragma unroll
        for (int ic = 0; ic < 3; ic++) {
#pragma unroll
            for (int i = 0; i < 3; i++) {
#pragma unroll
                for (int j = 0; j < 3; j++) {
                    float wv = wp[ic * 9 + i * 3 + j];
                    aA += xr[ic][i][j] * wv;
                    aB += xr[ic][i + 1][j] * wv;
                }
            }
        }
        int o = ((b * 64 + oc) << 16) + (h0 << 8) + w;
        feat[o]       = aA;
        feat[o + 256] = aB;
    }
}

// ---------------------------------------------------------------------------
// conv2 (unchanged)
// ---------------------------------------------------------------------------
__global__ __launch_bounds__(256) void conv2_kernel(const float* __restrict__ feat,
                                                    const float* __restrict__ wt2,
                                                    const float* __restrict__ ob,
                                                    float* __restrict__ offs) {
    __shared__ __align__(16) float w2[WT2_N];
    const int tid = threadIdx.x;
    {
        const float4* s4 = (const float4*)wt2;
        float4* d4 = (float4*)w2;
        for (int i = tid; i < WT2_N / 4; i += 256) d4[i] = s4[i];
    }
    __syncthreads();

    const int bx = blockIdx.x;
    const int b  = bx >> 7;
    const int h0 = (bx & 127) << 1;
    const int w  = tid;

    float accA[20], accB[20];
#pragma unroll
    for (int q = 0; q < 20; q++) {
        float bv = (q < 18) ? ob[q] : 0.f;
        accA[q] = bv;
        accB[q] = bv;
    }

    for (int ic = 0; ic < 64; ic++) {
        const float* fp = feat + ((size_t)(b * 64 + ic) << 16);
        float rv[4][3];
#pragma unroll
        for (int r = 0; r < 4; r++) {
            int row = h0 - 1 + r;
            bool rok = (unsigned)row < 256u;
#pragma unroll
            for (int j = 0; j < 3; j++) {
                int col = w - 1 + j;
                rv[r][j] = (rok && ((unsigned)col < 256u)) ? fp[(row << 8) + col] : 0.f;
            }
        }
        const float4* wrow = (const float4*)&w2[ic * 180];
#pragma unroll
        for (int t = 0; t < 9; t++) {
            const int i = t / 3, j = t - (t / 3) * 3;
            float fA = rv[i][j];
            float fB = rv[i + 1][j];
#pragma unroll
            for (int q = 0; q < 5; q++) {
                float4 wv = wrow[t * 5 + q];
                accA[q * 4 + 0] += fA * wv.x; accA[q * 4 + 1] += fA * wv.y;
                accA[q * 4 + 2] += fA * wv.z; accA[q * 4 + 3] += fA * wv.w;
                accB[q * 4 + 0] += fB * wv.x; accB[q * 4 + 1] += fB * wv.y;
                accB[q * 4 + 2] += fB * wv.z; accB[q * 4 + 3] += fB * wv.w;
            }
        }
    }

#pragma unroll
    for (int oc = 0; oc < 18; oc++) {
        int o = ((b * 18 + oc) << 16) + (h0 << 8) + w;
        offs[o]       = accA[oc];
        offs[o + 256] = accB[oc];
    }
}

// ---------------------------------------------------------------------------
// deform conv, MFMA, BARRIER-FREE. Block = 256 thr = 4 waves; 128 px x 64 oc.
// Wave-private pipeline: wave w samples px [32w,32w+32) x 64 ch into LDS
// smp[k2][px] (k2 = channel pair, row stride 130 dwords -> both writes and
// reads land 2 lanes/bank = conflict-free), then feeds its own MFMA A-frags.
// Intra-wave DS ordering (lgkmcnt) replaces __syncthreads entirely.
// Sampler lane: px = lane&31, chg = lane>>5 (32 channels each).
// All 18 offset-plane loads hoisted before the tap loop.
// Bilinear combine in packed float2 (v_pk_fma_f32) + packed bf16 convert.
// XCD swizzle keeps each XCD's feat band L2-resident (FETCH 893->43 MB).
// ---------------------------------------------------------------------------
__global__ __launch_bounds__(256) void deform_kernel(const float* __restrict__ feat,
                                                     const float* __restrict__ offs,
                                                     const unsigned short* __restrict__ wtf,
                                                     const float* __restrict__ db,
                                                     float* __restrict__ out) {
    __shared__ __align__(16) unsigned smp[32 * 130];   // [k2 0..31][px 0..127 pad130]
    const int tid  = threadIdx.x;
    const int lane = tid & 63;
    const int wave = tid >> 6;
    const int lm   = lane & 15;
    const int quad = lane >> 4;

    const int bx = blockIdx.x;
    const int strip = ((bx & 7) << 8) | (bx >> 3);
    const int wo_base = (strip & 1) << 7;
    const int ho = (strip >> 1) & 255;
    const int b  = strip >> 9;

    // sampler role: 32 consecutive px per wave, 32 channels per lane
    const int pxl    = lane & 31;
    const int chg    = lane >> 5;
    const int px_blk = wave * 32 + pxl;
    const int wo_s   = wo_base + px_blk;

    // hoist all 18 offset loads (removes per-tap L2 dependency)
    const float* opb = offs + (((size_t)b * 18) << 16) + (ho << 8) + wo_s;
    float offy[9], offx[9];
#pragma unroll
    for (int t = 0; t < 9; t++) {
        offy[t] = opb[(size_t)(2 * t) << 16];
        offx[t] = opb[(size_t)(2 * t + 1) << 16];
    }

    float4v acc[2][4];
#pragma unroll
    for (int mt = 0; mt < 2; mt++)
#pragma unroll
        for (int nt = 0; nt < 4; nt++) acc[mt][nt] = (float4v)0.f;

    const float* fb = feat + ((size_t)b << 22);            // uniform base
    const unsigned choff = ((unsigned)(chg * 32)) << 16;   // first channel offset

    for (int tap = 0; tap < 9; ++tap) {
        const int ky = tap / 3;
        const int kx = tap - 3 * ky;

        // ---- per-pixel coords & folded border coefficients ----
        float sy = (float)(ho - 1 + ky) + offy[tap];
        float sx = (float)(wo_s - 1 + kx) + offx[tap];
        float y0f = floorf(sy), x0f = floorf(sx);
        float dy = sy - y0f, dx = sx - x0f;
        int y0 = (int)y0f, x0 = (int)x0f;
        float wy0 = ((unsigned)y0 < 256u) ? (1.f - dy) : 0.f;
        float wy1 = ((unsigned)(y0 + 1) < 256u) ? dy : 0.f;
        float c0 = ((unsigned)x0 < 256u) ? (1.f - dx) : ((x0 == -1) ? dx : 0.f);
        float c1 = ((unsigned)x0 < 255u) ? dx : 0.f;
        int yb0 = y0 < 0 ? 0 : (y0 > 255 ? 255 : y0);
        int yb1 = (y0 + 1) < 0 ? 0 : ((y0 + 1) > 255 ? 255 : (y0 + 1));
        int xb  = x0 < 0 ? 0 : (x0 > 255 ? 255 : x0);
        const float w00 = wy0 * c0, w01 = wy0 * c1;
        const float w10 = wy1 * c0, w11 = wy1 * c1;
        const unsigned base0 = choff + (unsigned)((yb0 << 8) + xb);
        const unsigned base1 = choff + (unsigned)((yb1 << 8) + xb);

        // ---- sample 32 channels (16 pairs) -> wave-private LDS cols ----
        unsigned* sw = &smp[(chg * 16) * 130 + px_blk];
#pragma unroll 8
        for (int i = 0; i < 16; i++) {
            const f2 a0 = *(const f2*)(fb + base0 + ((unsigned)(2 * i) << 16));
            const f2 a1 = *(const f2*)(fb + base1 + ((unsigned)(2 * i) << 16));
            const f2 b0 = *(const f2*)(fb + base0 + ((unsigned)(2 * i + 1) << 16));
            const f2 b1 = *(const f2*)(fb + base1 + ((unsigned)(2 * i + 1) << 16));
            f2 P1 = {a0.x, b0.x};   // left  col, ch even/odd
            f2 P2 = {a0.y, b0.y};   // right col
            f2 P3 = {a1.x, b1.x};
            f2 P4 = {a1.y, b1.y};
            f2 G = P1 * w00 + P2 * w01 + P3 * w10 + P4 * w11;
            sw[i * 130] = pack_bf16x2(G.x, G.y);
        }

        // ---- consume (same wave; lgkmcnt orders DS ops, no barrier) ----
#pragma unroll
        for (int step = 0; step < 2; ++step) {
            const int ks = tap * 2 + step;
            short8 bfr[4];
            const unsigned short* wp = wtf + (size_t)(ks * 256 + lane) * 8;
#pragma unroll
            for (int nt = 0; nt < 4; nt++)
                bfr[nt] = *(const short8*)(wp + (nt << 9));
#pragma unroll
            for (int mt = 0; mt < 2; mt++) {
                const int pxr = wave * 32 + mt * 16 + lm;
                union { short8 v; unsigned u[4]; } af;
#pragma unroll
                for (int j = 0; j < 4; j++)
                    af.u[j] = smp[(step * 16 + quad * 4 + j) * 130 + pxr];
#pragma unroll
                for (int nt = 0; nt < 4; nt++)
                    acc[mt][nt] = __builtin_amdgcn_mfma_f32_16x16x32_bf16(
                        af.v, bfr[nt], acc[mt][nt], 0, 0, 0);
            }
        }
    }

    // epilogue: direct coalesced float4 stores (D: m=quad*4+reg consecutive px)
#pragma unroll
    for (int nt = 0; nt < 4; nt++) {
        int oc = nt * 16 + lm;
        float bv = db[oc];
        float* op = out + (((size_t)(b * 64 + oc)) << 16) + (ho << 8)
                  + wo_base + wave * 32 + quad * 4;
#pragma unroll
        for (int mt = 0; mt < 2; mt++) {
            float4 v = {acc[mt][nt][0] + bv, acc[mt][nt][1] + bv,
                        acc[mt][nt][2] + bv, acc[mt][nt][3] + bv};
            *(float4*)(op + mt * 16) = v;
        }
    }
}

// ---------------------------------------------------------------------------
extern "C" void kernel_launch(void* const* d_in, const int* in_sizes, int n_in,
                              void* d_out, int out_size, void* d_ws, size_t ws_size,
                              hipStream_t stream) {
    const float* x  = (const float*)d_in[0];
    const float* cw = (const float*)d_in[1];
    const float* cb = (const float*)d_in[2];
    const float* ow = (const float*)d_in[3];
    const float* ob = (const float*)d_in[4];
    const float* dw = (const float*)d_in[5];
    const float* db = (const float*)d_in[6];
    float* out = (float*)d_out;

    float* feat  = (float*)d_ws;                 // 64 MB
    float* offsb = feat + FEAT_N;                // 18 MB
    unsigned short* wtf = (unsigned short*)(offsb + OFFS_N);   // 72 KB bf16 frags
    float* wt2 = (float*)(wtf + WTF_N);          // 45 KB

    prep_weights<<<189, 256, 0, stream>>>(dw, ow, wtf, wt2);
    conv1_kernel<<<512, 256, 0, stream>>>(x, cw, cb, feat);
    conv2_kernel<<<512, 256, 0, stream>>>(feat, wt2, ob, offsb);
    deform_kernel<<<2048, 256, 0, stream>>>(feat, offsb, wtf, db, out);
}

// Round 6
// 381.767 us; speedup vs baseline: 1.3396x; 1.3396x over previous
//
#include <hip/hip_runtime.h>
#include <hip/hip_bf16.h>

// Problem constants: B=4, H=W=256, C=64, OC=64, K=3, PAD=1
#define FEAT_N (4*64*256*256)
#define OFFS_N (4*18*256*256)
#define WTF_N  (576*64)            // deform weights, bf16, MFMA-B-fragment order
#define WT2_N  (576*20)            // offset-conv weights transposed [ic*9+t][oc pad 20]

typedef __attribute__((ext_vector_type(8))) short short8;
typedef __attribute__((ext_vector_type(4))) float float4v;

__device__ __forceinline__ unsigned short f2bf(float f) {
    union { float f; unsigned u; } c; c.f = f;
    unsigned r = c.u + 0x7FFF + ((c.u >> 16) & 1);   // RNE
    return (unsigned short)(r >> 16);
}

__device__ __forceinline__ unsigned pack_bf16x2(float lo, float hi) {
    float2 v; v.x = lo; v.y = hi;
    __hip_bfloat162 h = __float22bfloat162_rn(v);     // v_cvt_pk_bf16_f32
    union { __hip_bfloat162 h; unsigned u; } c; c.h = h;
    return c.u;
}

__device__ __forceinline__ float bf_lo(unsigned u) { return __uint_as_float(u << 16); }
__device__ __forceinline__ float bf_hi(unsigned u) { return __uint_as_float(u & 0xFFFF0000u); }

// ---------------------------------------------------------------------------
// Weight prep (unchanged)
// ---------------------------------------------------------------------------
__global__ __launch_bounds__(256) void prep_weights(const float* __restrict__ dw,
                                                    const float* __restrict__ ow,
                                                    unsigned short* __restrict__ wtf,
                                                    float* __restrict__ wt2) {
    int idx = blockIdx.x * 256 + threadIdx.x;
    if (idx < WTF_N) {
        int j    = idx & 7;
        int lane = (idx >> 3) & 63;
        int nt   = (idx >> 9) & 3;
        int ks   = idx >> 11;
        int k    = ks * 32 + ((lane >> 4) << 3) + j;
        int tap  = k >> 6;
        int ic   = k & 63;
        int n    = nt * 16 + (lane & 15);
        wtf[idx] = f2bf(dw[n * 576 + ic * 9 + tap]);
    }
    int i2 = idx - WTF_N;
    if (i2 >= 0 && i2 < WT2_N) {
        int t  = i2 / 20;
        int oc = i2 - t * 20;
        wt2[i2] = (oc < 18) ? ow[oc * 576 + t] : 0.f;
    }
}

// ---------------------------------------------------------------------------
// conv1: also emits featp = bf16 channel-pair-interleaved copy
// featp element index: (b<<22) + (cp<<17) + (y<<9) + (x<<1) + (c&1)
// ---------------------------------------------------------------------------
__global__ __launch_bounds__(256) void conv1_kernel(const float* __restrict__ x,
                                                    const float* __restrict__ cw,
                                                    const float* __restrict__ cb,
                                                    float* __restrict__ feat,
                                                    unsigned short* __restrict__ featp) {
    __shared__ __align__(16) float wl[64 * 28];
    __shared__ float bl[64];
    const int tid = threadIdx.x;
    for (int i = tid; i < 64 * 28; i += 256) {
        int oc = i / 28;
        int t  = i - oc * 28;
        wl[i] = (t < 27) ? cw[oc * 27 + t] : 0.f;
    }
    if (tid < 64) bl[tid] = cb[tid];
    __syncthreads();

    const int bx = blockIdx.x;
    const int b  = bx >> 7;
    const int h0 = (bx & 127) << 1;
    const int w  = tid;

    float xr[3][4][3];
#pragma unroll
    for (int ic = 0; ic < 3; ic++) {
#pragma unroll
        for (int r = 0; r < 4; r++) {
            int row = h0 - 1 + r;
            bool rok = (unsigned)row < 256u;
#pragma unroll
            for (int j = 0; j < 3; j++) {
                int col = w - 1 + j;
                bool ok = rok && ((unsigned)col < 256u);
                xr[ic][r][j] = ok ? x[((b * 3 + ic) << 16) + (row << 8) + col] : 0.f;
            }
        }
    }

    for (int ocp = 0; ocp < 32; ocp++) {
        float aA0 = bl[2 * ocp],     aB0 = aA0;
        float aA1 = bl[2 * ocp + 1], aB1 = aA1;
        const float* wp0 = &wl[(2 * ocp) * 28];
        const float* wp1 = &wl[(2 * ocp + 1) * 28];
#pragma unroll
        for (int ic = 0; ic < 3; ic++) {
#pragma unroll
            for (int i = 0; i < 3; i++) {
#pragma unroll
                for (int j = 0; j < 3; j++) {
                    float xv0 = xr[ic][i][j];
                    float xv1 = xr[ic][i + 1][j];
                    float w0 = wp0[ic * 9 + i * 3 + j];
                    float w1 = wp1[ic * 9 + i * 3 + j];
                    aA0 += xv0 * w0; aB0 += xv1 * w0;
                    aA1 += xv0 * w1; aB1 += xv1 * w1;
                }
            }
        }
        int o = ((b * 64 + 2 * ocp) << 16) + (h0 << 8) + w;
        feat[o]               = aA0;
        feat[o + 256]         = aB0;
        feat[o + 65536]       = aA1;
        feat[o + 65536 + 256] = aB1;
        unsigned ep = ((unsigned)b << 22) + ((unsigned)ocp << 17) + (h0 << 9) + (w << 1);
        *(unsigned*)(featp + ep)       = pack_bf16x2(aA0, aA1);
        *(unsigned*)(featp + ep + 512) = pack_bf16x2(aB0, aB1);
    }
}

// ---------------------------------------------------------------------------
// conv2 (unchanged)
// ---------------------------------------------------------------------------
__global__ __launch_bounds__(256) void conv2_kernel(const float* __restrict__ feat,
                                                    const float* __restrict__ wt2,
                                                    const float* __restrict__ ob,
                                                    float* __restrict__ offs) {
    __shared__ __align__(16) float w2[WT2_N];
    const int tid = threadIdx.x;
    {
        const float4* s4 = (const float4*)wt2;
        float4* d4 = (float4*)w2;
        for (int i = tid; i < WT2_N / 4; i += 256) d4[i] = s4[i];
    }
    __syncthreads();

    const int bx = blockIdx.x;
    const int b  = bx >> 7;
    const int h0 = (bx & 127) << 1;
    const int w  = tid;

    float accA[20], accB[20];
#pragma unroll
    for (int q = 0; q < 20; q++) {
        float bv = (q < 18) ? ob[q] : 0.f;
        accA[q] = bv;
        accB[q] = bv;
    }

    for (int ic = 0; ic < 64; ic++) {
        const float* fp = feat + ((size_t)(b * 64 + ic) << 16);
        float rv[4][3];
#pragma unroll
        for (int r = 0; r < 4; r++) {
            int row = h0 - 1 + r;
            bool rok = (unsigned)row < 256u;
#pragma unroll
            for (int j = 0; j < 3; j++) {
                int col = w - 1 + j;
                rv[r][j] = (rok && ((unsigned)col < 256u)) ? fp[(row << 8) + col] : 0.f;
            }
        }
        const float4* wrow = (const float4*)&w2[ic * 180];
#pragma unroll
        for (int t = 0; t < 9; t++) {
            const int i = t / 3, j = t - (t / 3) * 3;
            float fA = rv[i][j];
            float fB = rv[i + 1][j];
#pragma unroll
            for (int q = 0; q < 5; q++) {
                float4 wv = wrow[t * 5 + q];
                accA[q * 4 + 0] += fA * wv.x; accA[q * 4 + 1] += fA * wv.y;
                accA[q * 4 + 2] += fA * wv.z; accA[q * 4 + 3] += fA * wv.w;
                accB[q * 4 + 0] += fB * wv.x; accB[q * 4 + 1] += fB * wv.y;
                accB[q * 4 + 2] += fB * wv.z; accB[q * 4 + 3] += fB * wv.w;
            }
        }
    }

#pragma unroll
    for (int oc = 0; oc < 18; oc++) {
        int o = ((b * 18 + oc) << 16) + (h0 << 8) + w;
        offs[o]       = accA[oc];
        offs[o + 256] = accB[oc];
    }
}

// ---------------------------------------------------------------------------
// deform conv, MFMA, barrier-free, register-pipelined gathers.
// Block = 256 thr = 4 waves; tile = 128 px x 64 oc; wave-private 32 px.
// Gathers read bf16 pair-interleaved featp (half bytes/lines vs fp32).
// Explicit pipeline: raw chunk c+1 and next-tap chunk in flight while chunk c
// is combined -> every vmcnt wait has >=400 cyc of work ahead of it.
// launch_bounds(256,3): ~170 VGPR budget for loads-in-flight.
// ---------------------------------------------------------------------------
__global__ __launch_bounds__(256, 3) void deform_kernel(const unsigned short* __restrict__ featp,
                                                        const float* __restrict__ offs,
                                                        const unsigned short* __restrict__ wtf,
                                                        const float* __restrict__ db,
                                                        float* __restrict__ out) {
    __shared__ __align__(16) unsigned smp[32 * 130];   // [k2 0..31][px 0..127 pad130]
    const int tid  = threadIdx.x;
    const int lane = tid & 63;
    const int wave = tid >> 6;
    const int lm   = lane & 15;
    const int quad = lane >> 4;

    const int bx = blockIdx.x;
    const int strip = ((bx & 7) << 8) | (bx >> 3);
    const int wo_base = (strip & 1) << 7;
    const int ho = (strip >> 1) & 255;
    const int b  = strip >> 9;

    const int pxl    = lane & 31;
    const int chg    = lane >> 5;
    const int px_blk = wave * 32 + pxl;
    const int wo_s   = wo_base + px_blk;

    const float* opb = offs + (((size_t)b * 18) << 16) + (ho << 8) + wo_s;
    const unsigned short* fpb = featp + ((size_t)b << 22) + ((size_t)chg << 21);

    float4v acc[2][4];
#pragma unroll
    for (int mt = 0; mt < 2; mt++)
#pragma unroll
        for (int nt = 0; nt < 4; nt++) acc[mt][nt] = (float4v)0.f;

    // ---- coord state (current tap) ----
    float w00, w01, w10, w11;
    unsigned e00, e01, e10, e11;
    float oyc = opb[0];
    float oxc = opb[1 << 16];
    float oyn, oxn;

    // raw gather double buffer: 8 iters x 4 corners each
    unsigned R0[8][4], R1[8][4];

#define COORDS(TAP, OY, OX)                                                      \
    {                                                                            \
        const int ky = (TAP) / 3, kx = (TAP) - 3 * ((TAP) / 3);                  \
        float sy = (float)(ho - 1 + ky) + (OY);                                  \
        float sx = (float)(wo_s - 1 + kx) + (OX);                                \
        float y0f = floorf(sy), x0f = floorf(sx);                                \
        float dy = sy - y0f, dx = sx - x0f;                                      \
        int y0 = (int)y0f, x0 = (int)x0f;                                        \
        float wy0 = ((unsigned)y0 < 256u) ? (1.f - dy) : 0.f;                    \
        float wy1 = ((unsigned)(y0 + 1) < 256u) ? dy : 0.f;                      \
        float wx0 = ((unsigned)x0 < 256u) ? (1.f - dx) : 0.f;                    \
        float wx1 = ((unsigned)(x0 + 1) < 256u) ? dx : 0.f;                      \
        int yb0 = y0 < 0 ? 0 : (y0 > 255 ? 255 : y0);                            \
        int yb1 = (y0 + 1) < 0 ? 0 : ((y0 + 1) > 255 ? 255 : (y0 + 1));          \
        int xb0 = x0 < 0 ? 0 : (x0 > 255 ? 255 : x0);                            \
        int xb1 = (x0 + 1) < 0 ? 0 : ((x0 + 1) > 255 ? 255 : (x0 + 1));          \
        w00 = wy0 * wx0; w01 = wy0 * wx1; w10 = wy1 * wx0; w11 = wy1 * wx1;      \
        e00 = (yb0 << 9) + (xb0 << 1); e01 = (yb0 << 9) + (xb1 << 1);            \
        e10 = (yb1 << 9) + (xb0 << 1); e11 = (yb1 << 9) + (xb1 << 1);            \
    }

#define ISSUE8(BUF, I0)                                                          \
    _Pragma("unroll")                                                            \
    for (int i = 0; i < 8; i++) {                                                \
        const unsigned p17 = ((unsigned)((I0) + i)) << 17;                       \
        BUF[i][0] = *(const unsigned*)(fpb + p17 + e00);                         \
        BUF[i][1] = *(const unsigned*)(fpb + p17 + e01);                         \
        BUF[i][2] = *(const unsigned*)(fpb + p17 + e10);                         \
        BUF[i][3] = *(const unsigned*)(fpb + p17 + e11);                         \
    }

#define COMBINE8(BUF, I0)                                                        \
    _Pragma("unroll")                                                            \
    for (int i = 0; i < 8; i++) {                                                \
        float g0 = w00 * bf_lo(BUF[i][0]) + w01 * bf_lo(BUF[i][1])               \
                 + w10 * bf_lo(BUF[i][2]) + w11 * bf_lo(BUF[i][3]);              \
        float g1 = w00 * bf_hi(BUF[i][0]) + w01 * bf_hi(BUF[i][1])               \
                 + w10 * bf_hi(BUF[i][2]) + w11 * bf_hi(BUF[i][3]);              \
        smp[(chg * 16 + (I0) + i) * 130 + px_blk] = pack_bf16x2(g0, g1);         \
    }

    COORDS(0, oyc, oxc);
    ISSUE8(R0, 0);

    for (int tap = 0; tap < 9; ++tap) {
        if (tap < 8) {                       // prefetch next tap's offsets early
            oyn = opb[(size_t)(2 * tap + 2) << 16];
            oxn = opb[(size_t)(2 * tap + 3) << 16];
        }
        ISSUE8(R1, 8);                       // chunk 1 of current tap
        COMBINE8(R0, 0);                     // waits chunk 0 (issued last iter)
        COMBINE8(R1, 8);                     // slack = combine of chunk 0
        if (tap < 8) {
            switch (tap + 1) {               // coords for next tap (w/e regs free now)
                case 1: COORDS(1, oyn, oxn); break;
                case 2: COORDS(2, oyn, oxn); break;
                case 3: COORDS(3, oyn, oxn); break;
                case 4: COORDS(4, oyn, oxn); break;
                case 5: COORDS(5, oyn, oxn); break;
                case 6: COORDS(6, oyn, oxn); break;
                case 7: COORDS(7, oyn, oxn); break;
                default: COORDS(8, oyn, oxn); break;
            }
            ISSUE8(R0, 0);                   // chunk 0 of next tap — in flight during MFMA
        }

        // ---- consume tap (same-wave DS ordering; no barrier) ----
#pragma unroll
        for (int step = 0; step < 2; ++step) {
            const int ks = tap * 2 + step;
            short8 bfr[4];
            const unsigned short* wp = wtf + (size_t)(ks * 256 + lane) * 8;
#pragma unroll
            for (int nt = 0; nt < 4; nt++)
                bfr[nt] = *(const short8*)(wp + (nt << 9));
#pragma unroll
            for (int mt = 0; mt < 2; mt++) {
                const int pxr = wave * 32 + mt * 16 + lm;
                union { short8 v; unsigned u[4]; } af;
#pragma unroll
                for (int j = 0; j < 4; j++)
                    af.u[j] = smp[(step * 16 + quad * 4 + j) * 130 + pxr];
#pragma unroll
                for (int nt = 0; nt < 4; nt++)
                    acc[mt][nt] = __builtin_amdgcn_mfma_f32_16x16x32_bf16(
                        af.v, bfr[nt], acc[mt][nt], 0, 0, 0);
            }
        }
    }

    // epilogue: direct coalesced float4 stores (D: m=quad*4+reg consecutive px)
#pragma unroll
    for (int nt = 0; nt < 4; nt++) {
        int oc = nt * 16 + lm;
        float bv = db[oc];
        float* op = out + (((size_t)(b * 64 + oc)) << 16) + (ho << 8)
                  + wo_base + wave * 32 + quad * 4;
#pragma unroll
        for (int mt = 0; mt < 2; mt++) {
            float4 v = {acc[mt][nt][0] + bv, acc[mt][nt][1] + bv,
                        acc[mt][nt][2] + bv, acc[mt][nt][3] + bv};
            *(float4*)(op + mt * 16) = v;
        }
    }
#undef COORDS
#undef ISSUE8
#undef COMBINE8
}

// ---------------------------------------------------------------------------
extern "C" void kernel_launch(void* const* d_in, const int* in_sizes, int n_in,
                              void* d_out, int out_size, void* d_ws, size_t ws_size,
                              hipStream_t stream) {
    const float* x  = (const float*)d_in[0];
    const float* cw = (const float*)d_in[1];
    const float* cb = (const float*)d_in[2];
    const float* ow = (const float*)d_in[3];
    const float* ob = (const float*)d_in[4];
    const float* dw = (const float*)d_in[5];
    const float* db = (const float*)d_in[6];
    float* out = (float*)d_out;

    float* feat  = (float*)d_ws;                         // 64 MB fp32 (conv2)
    float* offsb = feat + FEAT_N;                        // 18 MB
    unsigned short* featp = (unsigned short*)(offsb + OFFS_N);   // 33.5 MB bf16 pairs
    unsigned short* wtf = featp + FEAT_N;                // 72 KB bf16 frags
    float* wt2 = (float*)(wtf + WTF_N);                  // 45 KB

    prep_weights<<<189, 256, 0, stream>>>(dw, ow, wtf, wt2);
    conv1_kernel<<<512, 256, 0, stream>>>(x, cw, cb, feat, featp);
    conv2_kernel<<<512, 256, 0, stream>>>(feat, wt2, ob, offsb);
    deform_kernel<<<2048, 256, 0, stream>>>(featp, offsb, wtf, db, out);
}

// Round 7
// 328.549 us; speedup vs baseline: 1.5566x; 1.1620x over previous
//
#include <hip/hip_runtime.h>
#include <hip/hip_bf16.h>

// Problem constants: B=4, H=W=256, C=64, OC=64, K=3, PAD=1
#define FEAT_N (4*64*256*256)
#define OFFS_N (4*18*256*256)
#define WTF_N  (576*64)            // deform weights, bf16, MFMA-B-fragment order
#define WT2F_N (576*32)            // offset-conv weights, bf16 frags, N padded to 32

typedef __attribute__((ext_vector_type(8))) short short8;
typedef __attribute__((ext_vector_type(4))) float float4v;

__device__ __forceinline__ unsigned short f2bf(float f) {
    union { float f; unsigned u; } c; c.f = f;
    unsigned r = c.u + 0x7FFF + ((c.u >> 16) & 1);   // RNE
    return (unsigned short)(r >> 16);
}

__device__ __forceinline__ unsigned pack_bf16x2(float lo, float hi) {
    float2 v; v.x = lo; v.y = hi;
    __hip_bfloat162 h = __float22bfloat162_rn(v);
    union { __hip_bfloat162 h; unsigned u; } c; c.h = h;
    return c.u;
}

__device__ __forceinline__ float bf_lo(unsigned u) { return __uint_as_float(u << 16); }
__device__ __forceinline__ float bf_hi(unsigned u) { return __uint_as_float(u & 0xFFFF0000u); }

// ---------------------------------------------------------------------------
// Weight prep: deform weights -> wtf (B-frags, 4 N-tiles); offset-conv
// weights -> wt2f (B-frags, 2 N-tiles, oc>=18 zero).
// ---------------------------------------------------------------------------
__global__ __launch_bounds__(256) void prep_weights(const float* __restrict__ dw,
                                                    const float* __restrict__ ow,
                                                    unsigned short* __restrict__ wtf,
                                                    unsigned short* __restrict__ wt2f) {
    int idx = blockIdx.x * 256 + threadIdx.x;
    if (idx < WTF_N) {
        int j    = idx & 7;
        int lane = (idx >> 3) & 63;
        int nt   = (idx >> 9) & 3;
        int ks   = idx >> 11;
        int k    = ks * 32 + ((lane >> 4) << 3) + j;
        int tap  = k >> 6;
        int ic   = k & 63;
        int n    = nt * 16 + (lane & 15);
        wtf[idx] = f2bf(dw[n * 576 + ic * 9 + tap]);
    }
    int i2 = idx - WTF_N;
    if (i2 >= 0 && i2 < WT2F_N) {
        int j    = i2 & 7;
        int lane = (i2 >> 3) & 63;
        int nt   = (i2 >> 9) & 1;
        int ks   = i2 >> 10;
        int k    = ks * 32 + ((lane >> 4) << 3) + j;
        int tap  = k >> 6;
        int ic   = k & 63;
        int n    = nt * 16 + (lane & 15);
        wt2f[i2] = (n < 18) ? f2bf(ow[n * 576 + ic * 9 + tap]) : (unsigned short)0;
    }
}

// ---------------------------------------------------------------------------
// conv1: x[4,3,256,256] * w + b -> featp (bf16 channel-pair-interleaved ONLY)
// featp element index: (b<<22) + (cp<<17) + (y<<9) + (x<<1) + (c&1)
// ---------------------------------------------------------------------------
__global__ __launch_bounds__(256) void conv1_kernel(const float* __restrict__ x,
                                                    const float* __restrict__ cw,
                                                    const float* __restrict__ cb,
                                                    unsigned short* __restrict__ featp) {
    __shared__ __align__(16) float wl[64 * 28];
    __shared__ float bl[64];
    const int tid = threadIdx.x;
    for (int i = tid; i < 64 * 28; i += 256) {
        int oc = i / 28;
        int t  = i - oc * 28;
        wl[i] = (t < 27) ? cw[oc * 27 + t] : 0.f;
    }
    if (tid < 64) bl[tid] = cb[tid];
    __syncthreads();

    const int bx = blockIdx.x;
    const int b  = bx >> 7;
    const int h0 = (bx & 127) << 1;
    const int w  = tid;

    float xr[3][4][3];
#pragma unroll
    for (int ic = 0; ic < 3; ic++) {
#pragma unroll
        for (int r = 0; r < 4; r++) {
            int row = h0 - 1 + r;
            bool rok = (unsigned)row < 256u;
#pragma unroll
            for (int j = 0; j < 3; j++) {
                int col = w - 1 + j;
                bool ok = rok && ((unsigned)col < 256u);
                xr[ic][r][j] = ok ? x[((b * 3 + ic) << 16) + (row << 8) + col] : 0.f;
            }
        }
    }

    for (int ocp = 0; ocp < 32; ocp++) {
        float aA0 = bl[2 * ocp],     aB0 = aA0;
        float aA1 = bl[2 * ocp + 1], aB1 = aA1;
        const float* wp0 = &wl[(2 * ocp) * 28];
        const float* wp1 = &wl[(2 * ocp + 1) * 28];
#pragma unroll
        for (int ic = 0; ic < 3; ic++) {
#pragma unroll
            for (int i = 0; i < 3; i++) {
#pragma unroll
                for (int j = 0; j < 3; j++) {
                    float xv0 = xr[ic][i][j];
                    float xv1 = xr[ic][i + 1][j];
                    float w0 = wp0[ic * 9 + i * 3 + j];
                    float w1 = wp1[ic * 9 + i * 3 + j];
                    aA0 += xv0 * w0; aB0 += xv1 * w0;
                    aA1 += xv0 * w1; aB1 += xv1 * w1;
                }
            }
        }
        unsigned ep = ((unsigned)b << 22) + ((unsigned)ocp << 17) + (h0 << 9) + (w << 1);
        *(unsigned*)(featp + ep)       = pack_bf16x2(aA0, aA1);
        *(unsigned*)(featp + ep + 512) = pack_bf16x2(aB0, aB1);
    }
}

// ---------------------------------------------------------------------------
// conv2, MFMA on bf16 featp. Block = 256 thr = 4 waves; 128 px strip x 18 oc
// (N padded 32). Per ky: stage padded row smp[cp][132] (dense coalesced dword
// loads), then 3 kx x 2 K-steps of MFMA. A-frag col = px + kx (borders = 0).
// D: m=quad*4+reg px contiguous -> direct float4 stores for oc<18.
// ---------------------------------------------------------------------------
__global__ __launch_bounds__(256) void conv2_kernel(const unsigned short* __restrict__ featp,
                                                    const unsigned short* __restrict__ wt2f,
                                                    const float* __restrict__ ob,
                                                    float* __restrict__ offs) {
    __shared__ unsigned smp[32 * 132];   // [cp 0..31][col 0..131], col c -> x = wo_base-1+c
    const int tid  = threadIdx.x;
    const int lane = tid & 63;
    const int wave = tid >> 6;
    const int lm   = lane & 15;
    const int quad = lane >> 4;

    const int bx = blockIdx.x;
    const int strip = ((bx & 7) << 8) | (bx >> 3);
    const int wo_base = (strip & 1) << 7;
    const int ho = (strip >> 1) & 255;
    const int b  = strip >> 9;

    const unsigned* fpb = (const unsigned*)featp + ((size_t)b << 21);  // dword planes

    float4v acc[2][2];
#pragma unroll
    for (int mt = 0; mt < 2; mt++)
#pragma unroll
        for (int nt = 0; nt < 2; nt++) acc[mt][nt] = (float4v)0.f;

    const int cp_s  = tid >> 3;        // staging: 8 threads per channel-pair
    const int col_s = tid & 7;

    for (int ky = 0; ky < 3; ky++) {
        const int row = ho - 1 + ky;
        const bool rok = (unsigned)row < 256u;
        __syncthreads();               // previous ky's reads complete
        {
            const unsigned* src = fpb + (cp_s << 16) + (row << 8);
            unsigned* dst = &smp[cp_s * 132];
#pragma unroll
            for (int i = 0; i < 17; i++) {
                int c = col_s + 8 * i;
                if (c < 130) {
                    int xx = wo_base - 1 + c;
                    unsigned v = 0;
                    if (rok && (unsigned)xx < 256u) v = src[xx];
                    dst[c] = v;
                }
            }
        }
        __syncthreads();

#pragma unroll
        for (int kx = 0; kx < 3; kx++) {
#pragma unroll
            for (int step = 0; step < 2; step++) {
                const int ks = (ky * 3 + kx) * 2 + step;
                short8 bfr[2];
                const unsigned short* wp = wt2f + (size_t)(ks * 2) * 512 + lane * 8;
                bfr[0] = *(const short8*)(wp);
                bfr[1] = *(const short8*)(wp + 512);
#pragma unroll
                for (int mt = 0; mt < 2; mt++) {
                    const int col = wave * 32 + mt * 16 + lm + kx;
                    union { short8 v; unsigned u[4]; } af;
#pragma unroll
                    for (int j = 0; j < 4; j++)
                        af.u[j] = smp[(step * 16 + quad * 4 + j) * 132 + col];
#pragma unroll
                    for (int nt = 0; nt < 2; nt++)
                        acc[mt][nt] = __builtin_amdgcn_mfma_f32_16x16x32_bf16(
                            af.v, bfr[nt], acc[mt][nt], 0, 0, 0);
                }
            }
        }
    }

#pragma unroll
    for (int nt = 0; nt < 2; nt++) {
        int oc = nt * 16 + lm;
        if (oc < 18) {
            float bv = ob[oc];
            float* op = offs + (((size_t)(b * 18 + oc)) << 16) + (ho << 8)
                      + wo_base + wave * 32 + quad * 4;
#pragma unroll
            for (int mt = 0; mt < 2; mt++) {
                float4 v = {acc[mt][nt][0] + bv, acc[mt][nt][1] + bv,
                            acc[mt][nt][2] + bv, acc[mt][nt][3] + bv};
                *(float4*)(op + mt * 16) = v;
            }
        }
    }
}

// ---------------------------------------------------------------------------
// deform conv (unchanged from R6): MFMA, barrier-free, register-pipelined
// bf16-pair gathers, wave-private LDS, XCD swizzle.
// ---------------------------------------------------------------------------
__global__ __launch_bounds__(256, 3) void deform_kernel(const unsigned short* __restrict__ featp,
                                                        const float* __restrict__ offs,
                                                        const unsigned short* __restrict__ wtf,
                                                        const float* __restrict__ db,
                                                        float* __restrict__ out) {
    __shared__ __align__(16) unsigned smp[32 * 130];
    const int tid  = threadIdx.x;
    const int lane = tid & 63;
    const int wave = tid >> 6;
    const int lm   = lane & 15;
    const int quad = lane >> 4;

    const int bx = blockIdx.x;
    const int strip = ((bx & 7) << 8) | (bx >> 3);
    const int wo_base = (strip & 1) << 7;
    const int ho = (strip >> 1) & 255;
    const int b  = strip >> 9;

    const int pxl    = lane & 31;
    const int chg    = lane >> 5;
    const int px_blk = wave * 32 + pxl;
    const int wo_s   = wo_base + px_blk;

    const float* opb = offs + (((size_t)b * 18) << 16) + (ho << 8) + wo_s;
    const unsigned short* fpb = featp + ((size_t)b << 22) + ((size_t)chg << 21);

    float4v acc[2][4];
#pragma unroll
    for (int mt = 0; mt < 2; mt++)
#pragma unroll
        for (int nt = 0; nt < 4; nt++) acc[mt][nt] = (float4v)0.f;

    float w00, w01, w10, w11;
    unsigned e00, e01, e10, e11;
    float oyc = opb[0];
    float oxc = opb[1 << 16];
    float oyn, oxn;

    unsigned R0[8][4], R1[8][4];

#define COORDS(TAP, OY, OX)                                                      \
    {                                                                            \
        const int ky = (TAP) / 3, kx = (TAP) - 3 * ((TAP) / 3);                  \
        float sy = (float)(ho - 1 + ky) + (OY);                                  \
        float sx = (float)(wo_s - 1 + kx) + (OX);                                \
        float y0f = floorf(sy), x0f = floorf(sx);                                \
        float dy = sy - y0f, dx = sx - x0f;                                      \
        int y0 = (int)y0f, x0 = (int)x0f;                                        \
        float wy0 = ((unsigned)y0 < 256u) ? (1.f - dy) : 0.f;                    \
        float wy1 = ((unsigned)(y0 + 1) < 256u) ? dy : 0.f;                      \
        float wx0 = ((unsigned)x0 < 256u) ? (1.f - dx) : 0.f;                    \
        float wx1 = ((unsigned)(x0 + 1) < 256u) ? dx : 0.f;                      \
        int yb0 = y0 < 0 ? 0 : (y0 > 255 ? 255 : y0);                            \
        int yb1 = (y0 + 1) < 0 ? 0 : ((y0 + 1) > 255 ? 255 : (y0 + 1));          \
        int xb0 = x0 < 0 ? 0 : (x0 > 255 ? 255 : x0);                            \
        int xb1 = (x0 + 1) < 0 ? 0 : ((x0 + 1) > 255 ? 255 : (x0 + 1));          \
        w00 = wy0 * wx0; w01 = wy0 * wx1; w10 = wy1 * wx0; w11 = wy1 * wx1;      \
        e00 = (yb0 << 9) + (xb0 << 1); e01 = (yb0 << 9) + (xb1 << 1);            \
        e10 = (yb1 << 9) + (xb0 << 1); e11 = (yb1 << 9) + (xb1 << 1);            \
    }

#define ISSUE8(BUF, I0)                                                          \
    _Pragma("unroll")                                                            \
    for (int i = 0; i < 8; i++) {                                                \
        const unsigned p17 = ((unsigned)((I0) + i)) << 17;                       \
        BUF[i][0] = *(const unsigned*)(fpb + p17 + e00);                         \
        BUF[i][1] = *(const unsigned*)(fpb + p17 + e01);                         \
        BUF[i][2] = *(const unsigned*)(fpb + p17 + e10);                         \
        BUF[i][3] = *(const unsigned*)(fpb + p17 + e11);                         \
    }

#define COMBINE8(BUF, I0)                                                        \
    _Pragma("unroll")                                                            \
    for (int i = 0; i < 8; i++) {                                                \
        float g0 = w00 * bf_lo(BUF[i][0]) + w01 * bf_lo(BUF[i][1])               \
                 + w10 * bf_lo(BUF[i][2]) + w11 * bf_lo(BUF[i][3]);              \
        float g1 = w00 * bf_hi(BUF[i][0]) + w01 * bf_hi(BUF[i][1])               \
                 + w10 * bf_hi(BUF[i][2]) + w11 * bf_hi(BUF[i][3]);              \
        smp[(chg * 16 + (I0) + i) * 130 + px_blk] = pack_bf16x2(g0, g1);         \
    }

    COORDS(0, oyc, oxc);
    ISSUE8(R0, 0);

    for (int tap = 0; tap < 9; ++tap) {
        if (tap < 8) {
            oyn = opb[(size_t)(2 * tap + 2) << 16];
            oxn = opb[(size_t)(2 * tap + 3) << 16];
        }
        ISSUE8(R1, 8);
        COMBINE8(R0, 0);
        COMBINE8(R1, 8);
        if (tap < 8) {
            switch (tap + 1) {
                case 1: COORDS(1, oyn, oxn); break;
                case 2: COORDS(2, oyn, oxn); break;
                case 3: COORDS(3, oyn, oxn); break;
                case 4: COORDS(4, oyn, oxn); break;
                case 5: COORDS(5, oyn, oxn); break;
                case 6: COORDS(6, oyn, oxn); break;
                case 7: COORDS(7, oyn, oxn); break;
                default: COORDS(8, oyn, oxn); break;
            }
            ISSUE8(R0, 0);
        }

#pragma unroll
        for (int step = 0; step < 2; ++step) {
            const int ks = tap * 2 + step;
            short8 bfr[4];
            const unsigned short* wp = wtf + (size_t)(ks * 256 + lane) * 8;
#pragma unroll
            for (int nt = 0; nt < 4; nt++)
                bfr[nt] = *(const short8*)(wp + (nt << 9));
#pragma unroll
            for (int mt = 0; mt < 2; mt++) {
                const int pxr = wave * 32 + mt * 16 + lm;
                union { short8 v; unsigned u[4]; } af;
#pragma unroll
                for (int j = 0; j < 4; j++)
                    af.u[j] = smp[(step * 16 + quad * 4 + j) * 130 + pxr];
#pragma unroll
                for (int nt = 0; nt < 4; nt++)
                    acc[mt][nt] = __builtin_amdgcn_mfma_f32_16x16x32_bf16(
                        af.v, bfr[nt], acc[mt][nt], 0, 0, 0);
            }
        }
    }

#pragma unroll
    for (int nt = 0; nt < 4; nt++) {
        int oc = nt * 16 + lm;
        float bv = db[oc];
        float* op = out + (((size_t)(b * 64 + oc)) << 16) + (ho << 8)
                  + wo_base + wave * 32 + quad * 4;
#pragma unroll
        for (int mt = 0; mt < 2; mt++) {
            float4 v = {acc[mt][nt][0] + bv, acc[mt][nt][1] + bv,
                        acc[mt][nt][2] + bv, acc[mt][nt][3] + bv};
            *(float4*)(op + mt * 16) = v;
        }
    }
#undef COORDS
#undef ISSUE8
#undef COMBINE8
}

// ---------------------------------------------------------------------------
extern "C" void kernel_launch(void* const* d_in, const int* in_sizes, int n_in,
                              void* d_out, int out_size, void* d_ws, size_t ws_size,
                              hipStream_t stream) {
    const float* x  = (const float*)d_in[0];
    const float* cw = (const float*)d_in[1];
    const float* cb = (const float*)d_in[2];
    const float* ow = (const float*)d_in[3];
    const float* ob = (const float*)d_in[4];
    const float* dw = (const float*)d_in[5];
    const float* db = (const float*)d_in[6];
    float* out = (float*)d_out;

    unsigned short* featp = (unsigned short*)d_ws;       // 33.5 MB bf16 pairs
    float* offsb = (float*)(featp + FEAT_N);             // 18 MB
    unsigned short* wtf  = (unsigned short*)(offsb + OFFS_N);  // 72 KB
    unsigned short* wt2f = wtf + WTF_N;                  // 36 KB

    prep_weights<<<216, 256, 0, stream>>>(dw, ow, wtf, wt2f);
    conv1_kernel<<<512, 256, 0, stream>>>(x, cw, cb, featp);
    conv2_kernel<<<2048, 256, 0, stream>>>(featp, wt2f, ob, offsb);
    deform_kernel<<<2048, 256, 0, stream>>>(featp, offsb, wtf, db, out);
}